// Round 1
// baseline (3973.162 us; speedup 1.0000x reference)
//
#include <hip/hip_runtime.h>

#define NUSERS 100000
#define NITEMS 50000
#define NTOT   150000   // NUSERS + NITEMS
#define NBIC   20000
#define DIM    64

// ---------------------------------------------------------------------------
// acc = concat(user_emb, item_emb)   (float4-vectorized copy)
// ---------------------------------------------------------------------------
__global__ void init_acc_kernel(const float* __restrict__ user,
                                const float* __restrict__ item,
                                float* __restrict__ acc) {
    int i = blockIdx.x * blockDim.x + threadIdx.x;   // float4 index
    const int n4 = NTOT * DIM / 4;
    if (i >= n4) return;
    const int u4 = NUSERS * DIM / 4;
    float4 v = (i < u4) ? ((const float4*)user)[i]
                        : ((const float4*)item)[i - u4];
    ((float4*)acc)[i] = v;
}

// ---------------------------------------------------------------------------
// Edge-parallel COO SpMM:  y[row] += val * x[col]
// 16 threads per edge, each thread owns a float4 chunk of the 64-dim row.
// ---------------------------------------------------------------------------
__global__ void spmm_kernel(const int* __restrict__ row,
                            const int* __restrict__ col,
                            const float* __restrict__ val,
                            const float* __restrict__ x,
                            float* __restrict__ y, int nnz) {
    int t = blockIdx.x * blockDim.x + threadIdx.x;
    int e = t >> 4;
    if (e >= nnz) return;
    int c = (t & 15) << 2;
    int r  = row[e];
    int cc = col[e];
    float v = val[e];
    float4 xv = *(const float4*)(x + (long long)cc * DIM + c);
    float* yp = y + (long long)r * DIM + c;
    atomicAdd(yp + 0, v * xv.x);
    atomicAdd(yp + 1, v * xv.y);
    atomicAdd(yp + 2, v * xv.z);
    atomicAdd(yp + 3, v * xv.w);
}

// Layer-1 variant: the source matrix is the virtual concat(user_emb, item_emb)
__global__ void spmm_concat_kernel(const int* __restrict__ row,
                                   const int* __restrict__ col,
                                   const float* __restrict__ val,
                                   const float* __restrict__ user,
                                   const float* __restrict__ item,
                                   float* __restrict__ y, int nnz) {
    int t = blockIdx.x * blockDim.x + threadIdx.x;
    int e = t >> 4;
    if (e >= nnz) return;
    int c = (t & 15) << 2;
    int r  = row[e];
    int cc = col[e];
    float v = val[e];
    const float* src = (cc < NUSERS) ? (user + (long long)cc * DIM)
                                     : (item + (long long)(cc - NUSERS) * DIM);
    float4 xv = *(const float4*)(src + c);
    float* yp = y + (long long)r * DIM + c;
    atomicAdd(yp + 0, v * xv.x);
    atomicAdd(yp + 1, v * xv.y);
    atomicAdd(yp + 2, v * xv.z);
    atomicAdd(yp + 3, v * xv.w);
}

// acc += t   (elementwise, float4)
__global__ void add_kernel(float* __restrict__ acc,
                           const float* __restrict__ t, int n4) {
    int i = blockIdx.x * blockDim.x + threadIdx.x;
    if (i >= n4) return;
    float4 a = ((const float4*)acc)[i];
    float4 b = ((const float4*)t)[i];
    a.x += b.x; a.y += b.y; a.z += b.z; a.w += b.w;
    ((float4*)acc)[i] = a;
}

// deg[row] += val  (edge-parallel)
__global__ void degree_kernel(const int* __restrict__ row,
                              const float* __restrict__ val,
                              float* __restrict__ deg, int nnz) {
    int e = blockIdx.x * blockDim.x + threadIdx.x;
    if (e >= nnz) return;
    atomicAdd(deg + row[e], val[e]);
}

// bic[r] /= max-ish(deg[r])  with deg==0 -> 1
__global__ void scale_bic_kernel(float* __restrict__ bic,
                                 const float* __restrict__ deg) {
    int i = blockIdx.x * blockDim.x + threadIdx.x;   // float4 index
    const int n4 = NBIC * DIM / 4;
    if (i >= n4) return;
    int r = i >> 4;
    float d = deg[r];
    if (d == 0.0f) d = 1.0f;
    float inv = 1.0f / d;
    float4 v = ((const float4*)bic)[i];
    v.x *= inv; v.y *= inv; v.z *= inv; v.w *= inv;
    ((float4*)bic)[i] = v;
}

// out = acc*0.25 (+ ulocal/deg for user rows), writes both outputs
__global__ void final_kernel(const float* __restrict__ acc,
                             const float* __restrict__ ulocal,
                             const float* __restrict__ hu_deg,
                             float* __restrict__ out) {
    int i = blockIdx.x * blockDim.x + threadIdx.x;   // float4 index
    const int n4 = NTOT * DIM / 4;
    if (i >= n4) return;
    int node = i >> 4;
    float4 a = ((const float4*)acc)[i];
    float4 r;
    r.x = a.x * 0.25f; r.y = a.y * 0.25f; r.z = a.z * 0.25f; r.w = a.w * 0.25f;
    if (node < NUSERS) {
        float d = hu_deg[node];
        if (d == 0.0f) d = 1.0f;
        float inv = 1.0f / d;
        float4 ul = ((const float4*)ulocal)[i];
        r.x += ul.x * inv; r.y += ul.y * inv; r.z += ul.z * inv; r.w += ul.w * inv;
    }
    ((float4*)out)[i] = r;
}

extern "C" void kernel_launch(void* const* d_in, const int* in_sizes, int n_in,
                              void* d_out, int out_size, void* d_ws, size_t ws_size,
                              hipStream_t stream) {
    const float* user_emb = (const float*)d_in[0];
    const float* item_emb = (const float*)d_in[1];
    const float* adj_val  = (const float*)d_in[2];
    const float* hv_val   = (const float*)d_in[3];
    const float* hu_val   = (const float*)d_in[4];
    const int*   adj_row  = (const int*)d_in[5];
    const int*   adj_col  = (const int*)d_in[6];
    const int*   hv_row   = (const int*)d_in[7];
    const int*   hv_col   = (const int*)d_in[8];
    const int*   hu_row   = (const int*)d_in[9];
    const int*   hu_col   = (const int*)d_in[10];

    const int E_ADJ = in_sizes[2];
    const int E_HV  = in_sizes[3];
    const int E_HU  = in_sizes[4];

    // -------- workspace carve-up (bytes) --------
    char* ws = (char*)d_ws;
    const size_t SZ_NODE = (size_t)NTOT * DIM * sizeof(float);    // 38.4 MB
    float* acc    = (float*)(ws);                                  ws += SZ_NODE;
    float* T0     = (float*)(ws);                                  ws += SZ_NODE;
    float* T1     = (float*)(ws);                                  ws += SZ_NODE;
    float* bic    = (float*)(ws);                                  ws += (size_t)NBIC * DIM * sizeof(float);
    float* ulocal = (float*)(ws);                                  ws += (size_t)NUSERS * DIM * sizeof(float);
    float* hv_deg = (float*)(ws);                                  ws += (size_t)NBIC * sizeof(float);
    float* hu_deg = (float*)(ws);                                  ws += (size_t)NUSERS * sizeof(float);

    const int BLK = 256;
    const int n4_node = NTOT * DIM / 4;          // 2.4M float4
    const int g_node4 = (n4_node + BLK - 1) / BLK;
    const int g_adj   = (E_ADJ * 16 + BLK - 1) / BLK;
    const int g_hv    = (E_HV * 16 + BLK - 1) / BLK;
    const int g_hu    = (E_HU * 16 + BLK - 1) / BLK;

    // acc = all_emb
    init_acc_kernel<<<g_node4, BLK, 0, stream>>>(user_emb, item_emb, acc);

    // ---- layer 1: T0 = A * all_emb ; acc += T0
    hipMemsetAsync(T0, 0, SZ_NODE, stream);
    spmm_concat_kernel<<<g_adj, BLK, 0, stream>>>(adj_row, adj_col, adj_val,
                                                  user_emb, item_emb, T0, E_ADJ);
    add_kernel<<<g_node4, BLK, 0, stream>>>(acc, T0, n4_node);

    // ---- layer 2: T1 = A * T0 ; acc += T1
    hipMemsetAsync(T1, 0, SZ_NODE, stream);
    spmm_kernel<<<g_adj, BLK, 0, stream>>>(adj_row, adj_col, adj_val, T0, T1, E_ADJ);
    add_kernel<<<g_node4, BLK, 0, stream>>>(acc, T1, n4_node);

    // ---- layer 3: T0 = A * T1 ; acc += T0
    hipMemsetAsync(T0, 0, SZ_NODE, stream);
    spmm_kernel<<<g_adj, BLK, 0, stream>>>(adj_row, adj_col, adj_val, T1, T0, E_ADJ);
    add_kernel<<<g_node4, BLK, 0, stream>>>(acc, T0, n4_node);

    // ---- biclique features: bic = Hv * item_emb ; bic /= rowdeg(Hv)
    hipMemsetAsync(bic, 0, (size_t)NBIC * DIM * sizeof(float), stream);
    hipMemsetAsync(hv_deg, 0, (size_t)NBIC * sizeof(float), stream);
    spmm_kernel<<<g_hv, BLK, 0, stream>>>(hv_row, hv_col, hv_val, item_emb, bic, E_HV);
    degree_kernel<<<(E_HV + BLK - 1) / BLK, BLK, 0, stream>>>(hv_row, hv_val, hv_deg, E_HV);
    {
        const int n4 = NBIC * DIM / 4;
        scale_bic_kernel<<<(n4 + BLK - 1) / BLK, BLK, 0, stream>>>(bic, hv_deg);
    }

    // ---- u_local = Hu * bic ; (divide by rowdeg(Hu) fused into final)
    hipMemsetAsync(ulocal, 0, (size_t)NUSERS * DIM * sizeof(float), stream);
    hipMemsetAsync(hu_deg, 0, (size_t)NUSERS * sizeof(float), stream);
    spmm_kernel<<<g_hu, BLK, 0, stream>>>(hu_row, hu_col, hu_val, bic, ulocal, E_HU);
    degree_kernel<<<(E_HU + BLK - 1) / BLK, BLK, 0, stream>>>(hu_row, hu_val, hu_deg, E_HU);

    // ---- epilogue: out_user = acc/4 + ulocal/deg ; out_item = acc/4
    final_kernel<<<g_node4, BLK, 0, stream>>>(acc, ulocal, hu_deg, (float*)d_out);
}

// Round 2
// 576.702 us; speedup vs baseline: 6.8895x; 6.8895x over previous
//
#include <hip/hip_runtime.h>

#define NUSERS 100000
#define NITEMS 50000
#define NTOT   150000   // NUSERS + NITEMS
#define NBIC   20000
#define DIM    64
#define SCAN_B 1024

// ---------------------------------------------------------------------------
// CSR build: histogram -> 2-level exclusive scan -> scatter permute
// ---------------------------------------------------------------------------
__global__ void hist_kernel(const int* __restrict__ row, int* __restrict__ cnt, int nnz) {
    int e = blockIdx.x * blockDim.x + threadIdx.x;
    if (e < nnz) atomicAdd(&cnt[row[e]], 1);
}

// per-1024-block exclusive scan; block totals to bsum
__global__ void scan1_kernel(const int* __restrict__ cnt, int* __restrict__ ex,
                             int* __restrict__ bsum, int n) {
    __shared__ int s[SCAN_B];
    int tid = threadIdx.x;
    int g = blockIdx.x * SCAN_B + tid;
    int v = (g < n) ? cnt[g] : 0;
    s[tid] = v;
    __syncthreads();
    for (int off = 1; off < SCAN_B; off <<= 1) {
        int t = (tid >= off) ? s[tid - off] : 0;
        __syncthreads();
        s[tid] += t;
        __syncthreads();
    }
    if (g < n) ex[g] = s[tid] - v;                 // exclusive within block
    if (tid == SCAN_B - 1) bsum[blockIdx.x] = s[tid];
}

// single-block exclusive scan of block sums (nb <= 1024)
__global__ void scan2_kernel(int* __restrict__ bsum, int nb) {
    __shared__ int s[SCAN_B];
    int tid = threadIdx.x;
    int v = (tid < nb) ? bsum[tid] : 0;
    s[tid] = v;
    __syncthreads();
    for (int off = 1; off < SCAN_B; off <<= 1) {
        int t = (tid >= off) ? s[tid - off] : 0;
        __syncthreads();
        s[tid] += t;
        __syncthreads();
    }
    if (tid < nb) bsum[tid] = s[tid] - v;
}

// add block offsets; also initialize the scatter cursor
__global__ void scan3_kernel(int* __restrict__ ex, int* __restrict__ cursor,
                             const int* __restrict__ bsum, int n) {
    int g = blockIdx.x * blockDim.x + threadIdx.x;
    if (g < n) {
        int v = ex[g] + bsum[g >> 10];
        ex[g] = v;
        cursor[g] = v;
    }
}

__global__ void scatter_kernel(const int* __restrict__ row, const int* __restrict__ col,
                               const float* __restrict__ val, int* __restrict__ cursor,
                               int* __restrict__ ocol, float* __restrict__ oval, int nnz) {
    int e = blockIdx.x * blockDim.x + threadIdx.x;
    if (e >= nnz) return;
    int p = atomicAdd(&cursor[row[e]], 1);
    ocol[p] = col[e];
    oval[p] = val[e];
}

// ---------------------------------------------------------------------------
// Gather SpMMs: 16 threads per output row; each thread owns one float4 chunk.
// ---------------------------------------------------------------------------
__device__ __forceinline__ float4 f4zero() {
    float4 z; z.x = z.y = z.z = z.w = 0.f; return z;
}

// layer 1: source is the virtual concat(user_emb, item_emb)
__global__ void gather_layer1(const int* __restrict__ start, const int* __restrict__ cnt,
                              const int* __restrict__ col, const float* __restrict__ val,
                              const float* __restrict__ user, const float* __restrict__ item,
                              float* __restrict__ out) {
    int gid = blockIdx.x * (blockDim.x >> 4) + (threadIdx.x >> 4);
    if (gid >= NTOT) return;
    int c = (threadIdx.x & 15) << 2;
    int s = start[gid], n = cnt[gid];
    float4 acc = f4zero();
    for (int j = s; j < s + n; ++j) {
        int cc = col[j];
        float v = val[j];
        const float* src = (cc < NUSERS) ? user + (size_t)cc * DIM
                                         : item + (size_t)(cc - NUSERS) * DIM;
        float4 xv = *(const float4*)(src + c);
        acc.x += v * xv.x; acc.y += v * xv.y; acc.z += v * xv.z; acc.w += v * xv.w;
    }
    *(float4*)(out + (size_t)gid * DIM + c) = acc;
}

// generic gather: out[row] = sum val * x[col]
__global__ void gather_plain(const int* __restrict__ start, const int* __restrict__ cnt,
                             const int* __restrict__ col, const float* __restrict__ val,
                             const float* __restrict__ x, float* __restrict__ out, int nrows) {
    int gid = blockIdx.x * (blockDim.x >> 4) + (threadIdx.x >> 4);
    if (gid >= nrows) return;
    int c = (threadIdx.x & 15) << 2;
    int s = start[gid], n = cnt[gid];
    float4 acc = f4zero();
    for (int j = s; j < s + n; ++j) {
        int cc = col[j];
        float v = val[j];
        float4 xv = *(const float4*)(x + (size_t)cc * DIM + c);
        acc.x += v * xv.x; acc.y += v * xv.y; acc.z += v * xv.z; acc.w += v * xv.w;
    }
    *(float4*)(out + (size_t)gid * DIM + c) = acc;
}

// gather + row-degree normalization fused (deg = sum val, 0 -> 1)
__global__ void gather_norm(const int* __restrict__ start, const int* __restrict__ cnt,
                            const int* __restrict__ col, const float* __restrict__ val,
                            const float* __restrict__ x, float* __restrict__ out, int nrows) {
    int gid = blockIdx.x * (blockDim.x >> 4) + (threadIdx.x >> 4);
    if (gid >= nrows) return;
    int c = (threadIdx.x & 15) << 2;
    int s = start[gid], n = cnt[gid];
    float4 acc = f4zero();
    float deg = 0.f;
    for (int j = s; j < s + n; ++j) {
        int cc = col[j];
        float v = val[j];
        deg += v;
        float4 xv = *(const float4*)(x + (size_t)cc * DIM + c);
        acc.x += v * xv.x; acc.y += v * xv.y; acc.z += v * xv.z; acc.w += v * xv.w;
    }
    if (deg == 0.f) deg = 1.f;
    float inv = 1.f / deg;
    acc.x *= inv; acc.y *= inv; acc.z *= inv; acc.w *= inv;
    *(float4*)(out + (size_t)gid * DIM + c) = acc;
}

// layer 3 + full epilogue: out = 0.25*(x0 + e1 + e2 + e3) [+ ulocal for users]
// e3 gathered from T1; x0 is virtual concat; ulocal already deg-normalized.
__global__ void gather_final(const int* __restrict__ start, const int* __restrict__ cnt,
                             const int* __restrict__ col, const float* __restrict__ val,
                             const float* __restrict__ T0, const float* __restrict__ T1,
                             const float* __restrict__ user, const float* __restrict__ item,
                             const float* __restrict__ ulocal, float* __restrict__ out) {
    int gid = blockIdx.x * (blockDim.x >> 4) + (threadIdx.x >> 4);
    if (gid >= NTOT) return;
    int c = (threadIdx.x & 15) << 2;
    int s = start[gid], n = cnt[gid];
    float4 acc = f4zero();
    for (int j = s; j < s + n; ++j) {
        int cc = col[j];
        float v = val[j];
        float4 xv = *(const float4*)(T1 + (size_t)cc * DIM + c);
        acc.x += v * xv.x; acc.y += v * xv.y; acc.z += v * xv.z; acc.w += v * xv.w;
    }
    size_t o = (size_t)gid * DIM + c;
    float4 x0 = (gid < NUSERS) ? *(const float4*)(user + o)
                               : *(const float4*)(item + o - (size_t)NUSERS * DIM);
    float4 t0 = *(const float4*)(T0 + o);
    float4 t1 = *(const float4*)(T1 + o);
    float4 r;
    r.x = 0.25f * (x0.x + t0.x + t1.x + acc.x);
    r.y = 0.25f * (x0.y + t0.y + t1.y + acc.y);
    r.z = 0.25f * (x0.z + t0.z + t1.z + acc.z);
    r.w = 0.25f * (x0.w + t0.w + t1.w + acc.w);
    if (gid < NUSERS) {
        float4 ul = *(const float4*)(ulocal + o);
        r.x += ul.x; r.y += ul.y; r.z += ul.z; r.w += ul.w;
    }
    *(float4*)(out + o) = r;
}

// ---------------------------------------------------------------------------
extern "C" void kernel_launch(void* const* d_in, const int* in_sizes, int n_in,
                              void* d_out, int out_size, void* d_ws, size_t ws_size,
                              hipStream_t stream) {
    const float* user_emb = (const float*)d_in[0];
    const float* item_emb = (const float*)d_in[1];
    const float* adj_val  = (const float*)d_in[2];
    const float* hv_val   = (const float*)d_in[3];
    const float* hu_val   = (const float*)d_in[4];
    const int*   adj_row  = (const int*)d_in[5];
    const int*   adj_col  = (const int*)d_in[6];
    const int*   hv_row   = (const int*)d_in[7];
    const int*   hv_col   = (const int*)d_in[8];
    const int*   hu_row   = (const int*)d_in[9];
    const int*   hu_col   = (const int*)d_in[10];

    const int E_ADJ = in_sizes[2];
    const int E_HV  = in_sizes[3];
    const int E_HU  = in_sizes[4];

    // -------- workspace carve-up (256B-aligned) --------
    char* ws = (char*)d_ws;
    auto alloc = [&](size_t bytes) -> char* {
        char* p = ws;
        ws += (bytes + 255) & ~(size_t)255;
        return p;
    };
    const size_t SZ_NODE = (size_t)NTOT * DIM * sizeof(float);   // 38.4 MB
    float* T0      = (float*)alloc(SZ_NODE);
    float* T1      = (float*)alloc(SZ_NODE);
    float* bic     = (float*)alloc((size_t)NBIC * DIM * sizeof(float));
    float* ulocal  = (float*)alloc((size_t)NUSERS * DIM * sizeof(float));
    // adj CSR
    int*   a_cnt    = (int*)alloc(NTOT * sizeof(int));
    int*   a_start  = (int*)alloc(NTOT * sizeof(int));
    int*   a_cursor = (int*)alloc(NTOT * sizeof(int));
    int*   a_col    = (int*)alloc((size_t)E_ADJ * sizeof(int));
    float* a_val    = (float*)alloc((size_t)E_ADJ * sizeof(float));
    // hv CSR
    int*   v_cnt    = (int*)alloc(NBIC * sizeof(int));
    int*   v_start  = (int*)alloc(NBIC * sizeof(int));
    int*   v_cursor = (int*)alloc(NBIC * sizeof(int));
    int*   v_col    = (int*)alloc((size_t)E_HV * sizeof(int));
    float* v_val    = (float*)alloc((size_t)E_HV * sizeof(float));
    // hu CSR
    int*   u_cnt    = (int*)alloc(NUSERS * sizeof(int));
    int*   u_start  = (int*)alloc(NUSERS * sizeof(int));
    int*   u_cursor = (int*)alloc(NUSERS * sizeof(int));
    int*   u_col    = (int*)alloc((size_t)E_HU * sizeof(int));
    float* u_val    = (float*)alloc((size_t)E_HU * sizeof(float));
    // scan scratch
    int*   bsum     = (int*)alloc(SCAN_B * sizeof(int));

    const int BLK = 256;
    auto cdiv = [](int a, int b) { return (a + b - 1) / b; };

    // ---- build CSR for each graph ----
    struct Csr { const int* row; const int* col; const float* val;
                 int* cnt; int* start; int* cursor; int* ocol; float* oval;
                 int nnz; int nrows; };
    Csr graphs[3] = {
        { adj_row, adj_col, adj_val, a_cnt, a_start, a_cursor, a_col, a_val, E_ADJ, NTOT   },
        { hv_row,  hv_col,  hv_val,  v_cnt, v_start, v_cursor, v_col, v_val, E_HV,  NBIC   },
        { hu_row,  hu_col,  hu_val,  u_cnt, u_start, u_cursor, u_col, u_val, E_HU,  NUSERS },
    };
    for (int g = 0; g < 3; ++g) {
        Csr& G = graphs[g];
        hipMemsetAsync(G.cnt, 0, (size_t)G.nrows * sizeof(int), stream);
        hist_kernel<<<cdiv(G.nnz, BLK), BLK, 0, stream>>>(G.row, G.cnt, G.nnz);
        int nb = cdiv(G.nrows, SCAN_B);
        scan1_kernel<<<nb, SCAN_B, 0, stream>>>(G.cnt, G.start, bsum, G.nrows);
        scan2_kernel<<<1, SCAN_B, 0, stream>>>(bsum, nb);
        scan3_kernel<<<cdiv(G.nrows, BLK), BLK, 0, stream>>>(G.start, G.cursor, bsum, G.nrows);
        scatter_kernel<<<cdiv(G.nnz, BLK), BLK, 0, stream>>>(G.row, G.col, G.val, G.cursor,
                                                             G.ocol, G.oval, G.nnz);
    }

    // rows per 256-thread block in gather kernels
    const int RPB = BLK >> 4;   // 16

    // ---- layer 1: T0 = A * concat(user,item)
    gather_layer1<<<cdiv(NTOT, RPB), BLK, 0, stream>>>(a_start, a_cnt, a_col, a_val,
                                                       user_emb, item_emb, T0);
    // ---- layer 2: T1 = A * T0
    gather_plain<<<cdiv(NTOT, RPB), BLK, 0, stream>>>(a_start, a_cnt, a_col, a_val,
                                                      T0, T1, NTOT);
    // ---- biclique: bic = normalize(Hv * item_emb)
    gather_norm<<<cdiv(NBIC, RPB), BLK, 0, stream>>>(v_start, v_cnt, v_col, v_val,
                                                     item_emb, bic, NBIC);
    // ---- u_local = normalize(Hu * bic)
    gather_norm<<<cdiv(NUSERS, RPB), BLK, 0, stream>>>(u_start, u_cnt, u_col, u_val,
                                                       bic, ulocal, NUSERS);
    // ---- layer 3 + epilogue -> out
    gather_final<<<cdiv(NTOT, RPB), BLK, 0, stream>>>(a_start, a_cnt, a_col, a_val,
                                                      T0, T1, user_emb, item_emb,
                                                      ulocal, (float*)d_out);
}

// Round 3
// 539.792 us; speedup vs baseline: 7.3605x; 1.0684x over previous
//
#include <hip/hip_runtime.h>

#define NUSERS 100000
#define NITEMS 50000
#define NTOT   150000   // NUSERS + NITEMS
#define NBIC   20000
#define DIM    64
#define SCAN_B 1024

// concatenated row space: [adj rows | hv rows | hu rows]
#define HV_BASE  NTOT
#define HU_BASE  (NTOT + NBIC)
#define NROWS_ALL (NTOT + NBIC + NUSERS)   // 270000

// ---------------------------------------------------------------------------
// Fused CSR build over all three graphs (concatenated row space, one packed
// edge array). histogram -> 2-level exclusive scan -> packed int2 scatter.
// ---------------------------------------------------------------------------
__global__ void hist_fused(const int* __restrict__ adj_row,
                           const int* __restrict__ hv_row,
                           const int* __restrict__ hu_row,
                           int* __restrict__ cnt,
                           int e_adj, int e_hv, int e_hu) {
    int t = blockIdx.x * blockDim.x + threadIdx.x;
    int r;
    if (t < e_adj)                    r = adj_row[t];
    else if (t < e_adj + e_hv)        r = HV_BASE + hv_row[t - e_adj];
    else if (t < e_adj + e_hv + e_hu) r = HU_BASE + hu_row[t - e_adj - e_hv];
    else return;
    atomicAdd(&cnt[r], 1);
}

// per-1024-block exclusive scan; block totals to bsum
__global__ void scan1_kernel(const int* __restrict__ cnt, int* __restrict__ ex,
                             int* __restrict__ bsum, int n) {
    __shared__ int s[SCAN_B];
    int tid = threadIdx.x;
    int g = blockIdx.x * SCAN_B + tid;
    int v = (g < n) ? cnt[g] : 0;
    s[tid] = v;
    __syncthreads();
    for (int off = 1; off < SCAN_B; off <<= 1) {
        int t = (tid >= off) ? s[tid - off] : 0;
        __syncthreads();
        s[tid] += t;
        __syncthreads();
    }
    if (g < n) ex[g] = s[tid] - v;                 // exclusive within block
    if (tid == SCAN_B - 1) bsum[blockIdx.x] = s[tid];
}

// single-block exclusive scan of block sums (nb <= 1024)
__global__ void scan2_kernel(int* __restrict__ bsum, int nb) {
    __shared__ int s[SCAN_B];
    int tid = threadIdx.x;
    int v = (tid < nb) ? bsum[tid] : 0;
    s[tid] = v;
    __syncthreads();
    for (int off = 1; off < SCAN_B; off <<= 1) {
        int t = (tid >= off) ? s[tid - off] : 0;
        __syncthreads();
        s[tid] += t;
        __syncthreads();
    }
    if (tid < nb) bsum[tid] = s[tid] - v;
}

// add block offsets; also initialize the scatter cursor
__global__ void scan3_kernel(int* __restrict__ ex, int* __restrict__ cursor,
                             const int* __restrict__ bsum, int n) {
    int g = blockIdx.x * blockDim.x + threadIdx.x;
    if (g < n) {
        int v = ex[g] + bsum[g >> 10];
        ex[g] = v;
        cursor[g] = v;
    }
}

// one packed 8B write per edge into the single concatenated edge array
__global__ void scatter_fused(const int* __restrict__ adj_row, const int* __restrict__ adj_col,
                              const float* __restrict__ adj_val,
                              const int* __restrict__ hv_row, const int* __restrict__ hv_col,
                              const float* __restrict__ hv_val,
                              const int* __restrict__ hu_row, const int* __restrict__ hu_col,
                              const float* __restrict__ hu_val,
                              int* __restrict__ cursor, int2* __restrict__ edges,
                              int e_adj, int e_hv, int e_hu) {
    int t = blockIdx.x * blockDim.x + threadIdx.x;
    int r, c;
    float v;
    if (t < e_adj) {
        r = adj_row[t]; c = adj_col[t]; v = adj_val[t];
    } else if (t < e_adj + e_hv) {
        int i = t - e_adj;
        r = HV_BASE + hv_row[i]; c = hv_col[i]; v = hv_val[i];
    } else if (t < e_adj + e_hv + e_hu) {
        int i = t - e_adj - e_hv;
        r = HU_BASE + hu_row[i]; c = hu_col[i]; v = hu_val[i];
    } else return;
    int p = atomicAdd(&cursor[r], 1);
    edges[p] = make_int2(c, __float_as_int(v));
}

// ---------------------------------------------------------------------------
// Gather SpMMs: 16 threads per output row; each thread owns one float4 chunk.
// edges[] holds packed (col, val); start/cnt are absolute into edges[].
// ---------------------------------------------------------------------------
__device__ __forceinline__ float4 f4zero() {
    float4 z; z.x = z.y = z.z = z.w = 0.f; return z;
}

// layer 1: source is the virtual concat(user_emb, item_emb)
__global__ void gather_layer1(const int* __restrict__ start, const int* __restrict__ cnt,
                              const int2* __restrict__ edges,
                              const float* __restrict__ user, const float* __restrict__ item,
                              float* __restrict__ out) {
    int gid = blockIdx.x * (blockDim.x >> 4) + (threadIdx.x >> 4);
    if (gid >= NTOT) return;
    int c = (threadIdx.x & 15) << 2;
    int s = start[gid], n = cnt[gid];
    float4 acc = f4zero();
    for (int j = s; j < s + n; ++j) {
        int2 e = edges[j];
        int cc = e.x;
        float v = __int_as_float(e.y);
        const float* src = (cc < NUSERS) ? user + (size_t)cc * DIM
                                         : item + (size_t)(cc - NUSERS) * DIM;
        float4 xv = *(const float4*)(src + c);
        acc.x += v * xv.x; acc.y += v * xv.y; acc.z += v * xv.z; acc.w += v * xv.w;
    }
    *(float4*)(out + (size_t)gid * DIM + c) = acc;
}

// generic gather: out[row] = sum val * x[col]
__global__ void gather_plain(const int* __restrict__ start, const int* __restrict__ cnt,
                             const int2* __restrict__ edges,
                             const float* __restrict__ x, float* __restrict__ out, int nrows) {
    int gid = blockIdx.x * (blockDim.x >> 4) + (threadIdx.x >> 4);
    if (gid >= nrows) return;
    int c = (threadIdx.x & 15) << 2;
    int s = start[gid], n = cnt[gid];
    float4 acc = f4zero();
    for (int j = s; j < s + n; ++j) {
        int2 e = edges[j];
        int cc = e.x;
        float v = __int_as_float(e.y);
        float4 xv = *(const float4*)(x + (size_t)cc * DIM + c);
        acc.x += v * xv.x; acc.y += v * xv.y; acc.z += v * xv.z; acc.w += v * xv.w;
    }
    *(float4*)(out + (size_t)gid * DIM + c) = acc;
}

// gather + row-degree normalization fused (deg = sum val, 0 -> 1)
__global__ void gather_norm(const int* __restrict__ start, const int* __restrict__ cnt,
                            const int2* __restrict__ edges,
                            const float* __restrict__ x, float* __restrict__ out, int nrows) {
    int gid = blockIdx.x * (blockDim.x >> 4) + (threadIdx.x >> 4);
    if (gid >= nrows) return;
    int c = (threadIdx.x & 15) << 2;
    int s = start[gid], n = cnt[gid];
    float4 acc = f4zero();
    float deg = 0.f;
    for (int j = s; j < s + n; ++j) {
        int2 e = edges[j];
        int cc = e.x;
        float v = __int_as_float(e.y);
        deg += v;
        float4 xv = *(const float4*)(x + (size_t)cc * DIM + c);
        acc.x += v * xv.x; acc.y += v * xv.y; acc.z += v * xv.z; acc.w += v * xv.w;
    }
    if (deg == 0.f) deg = 1.f;
    float inv = 1.f / deg;
    acc.x *= inv; acc.y *= inv; acc.z *= inv; acc.w *= inv;
    *(float4*)(out + (size_t)gid * DIM + c) = acc;
}

// layer 3 + full epilogue: out = 0.25*(x0 + e1 + e2 + e3) [+ ulocal for users]
__global__ void gather_final(const int* __restrict__ start, const int* __restrict__ cnt,
                             const int2* __restrict__ edges,
                             const float* __restrict__ T0, const float* __restrict__ T1,
                             const float* __restrict__ user, const float* __restrict__ item,
                             const float* __restrict__ ulocal, float* __restrict__ out) {
    int gid = blockIdx.x * (blockDim.x >> 4) + (threadIdx.x >> 4);
    if (gid >= NTOT) return;
    int c = (threadIdx.x & 15) << 2;
    int s = start[gid], n = cnt[gid];
    float4 acc = f4zero();
    for (int j = s; j < s + n; ++j) {
        int2 e = edges[j];
        int cc = e.x;
        float v = __int_as_float(e.y);
        float4 xv = *(const float4*)(T1 + (size_t)cc * DIM + c);
        acc.x += v * xv.x; acc.y += v * xv.y; acc.z += v * xv.z; acc.w += v * xv.w;
    }
    size_t o = (size_t)gid * DIM + c;
    float4 x0 = (gid < NUSERS) ? *(const float4*)(user + o)
                               : *(const float4*)(item + o - (size_t)NUSERS * DIM);
    float4 t0 = *(const float4*)(T0 + o);
    float4 t1 = *(const float4*)(T1 + o);
    float4 r;
    r.x = 0.25f * (x0.x + t0.x + t1.x + acc.x);
    r.y = 0.25f * (x0.y + t0.y + t1.y + acc.y);
    r.z = 0.25f * (x0.z + t0.z + t1.z + acc.z);
    r.w = 0.25f * (x0.w + t0.w + t1.w + acc.w);
    if (gid < NUSERS) {
        float4 ul = *(const float4*)(ulocal + o);
        r.x += ul.x; r.y += ul.y; r.z += ul.z; r.w += ul.w;
    }
    *(float4*)(out + o) = r;
}

// ---------------------------------------------------------------------------
extern "C" void kernel_launch(void* const* d_in, const int* in_sizes, int n_in,
                              void* d_out, int out_size, void* d_ws, size_t ws_size,
                              hipStream_t stream) {
    const float* user_emb = (const float*)d_in[0];
    const float* item_emb = (const float*)d_in[1];
    const float* adj_val  = (const float*)d_in[2];
    const float* hv_val   = (const float*)d_in[3];
    const float* hu_val   = (const float*)d_in[4];
    const int*   adj_row  = (const int*)d_in[5];
    const int*   adj_col  = (const int*)d_in[6];
    const int*   hv_row   = (const int*)d_in[7];
    const int*   hv_col   = (const int*)d_in[8];
    const int*   hu_row   = (const int*)d_in[9];
    const int*   hu_col   = (const int*)d_in[10];

    const int E_ADJ = in_sizes[2];
    const int E_HV  = in_sizes[3];
    const int E_HU  = in_sizes[4];
    const int E_ALL = E_ADJ + E_HV + E_HU;

    // -------- workspace carve-up (256B-aligned) --------
    char* ws = (char*)d_ws;
    auto alloc = [&](size_t bytes) -> char* {
        char* p = ws;
        ws += (bytes + 255) & ~(size_t)255;
        return p;
    };
    const size_t SZ_NODE = (size_t)NTOT * DIM * sizeof(float);   // 38.4 MB
    float* T0      = (float*)alloc(SZ_NODE);
    float* T1      = (float*)alloc(SZ_NODE);
    float* bic     = (float*)alloc((size_t)NBIC * DIM * sizeof(float));
    float* ulocal  = (float*)alloc((size_t)NUSERS * DIM * sizeof(float));
    int*   cnt     = (int*)alloc((size_t)NROWS_ALL * sizeof(int));
    int*   start   = (int*)alloc((size_t)NROWS_ALL * sizeof(int));
    int*   cursor  = (int*)alloc((size_t)NROWS_ALL * sizeof(int));
    int2*  edges   = (int2*)alloc((size_t)E_ALL * sizeof(int2));
    int*   bsum    = (int*)alloc(SCAN_B * sizeof(int));

    const int BLK = 256;
    auto cdiv = [](int a, int b) { return (a + b - 1) / b; };

    // ---- fused CSR build ----
    hipMemsetAsync(cnt, 0, (size_t)NROWS_ALL * sizeof(int), stream);
    hist_fused<<<cdiv(E_ALL, BLK), BLK, 0, stream>>>(adj_row, hv_row, hu_row,
                                                     cnt, E_ADJ, E_HV, E_HU);
    int nb = cdiv(NROWS_ALL, SCAN_B);
    scan1_kernel<<<nb, SCAN_B, 0, stream>>>(cnt, start, bsum, NROWS_ALL);
    scan2_kernel<<<1, SCAN_B, 0, stream>>>(bsum, nb);
    scan3_kernel<<<cdiv(NROWS_ALL, BLK), BLK, 0, stream>>>(start, cursor, bsum, NROWS_ALL);
    scatter_fused<<<cdiv(E_ALL, BLK), BLK, 0, stream>>>(adj_row, adj_col, adj_val,
                                                        hv_row, hv_col, hv_val,
                                                        hu_row, hu_col, hu_val,
                                                        cursor, edges, E_ADJ, E_HV, E_HU);

    // rows per 256-thread block in gather kernels
    const int RPB = BLK >> 4;   // 16

    // ---- layer 1: T0 = A * concat(user,item)
    gather_layer1<<<cdiv(NTOT, RPB), BLK, 0, stream>>>(start, cnt, edges,
                                                       user_emb, item_emb, T0);
    // ---- layer 2: T1 = A * T0
    gather_plain<<<cdiv(NTOT, RPB), BLK, 0, stream>>>(start, cnt, edges, T0, T1, NTOT);
    // ---- biclique: bic = normalize(Hv * item_emb)
    gather_norm<<<cdiv(NBIC, RPB), BLK, 0, stream>>>(start + HV_BASE, cnt + HV_BASE, edges,
                                                     item_emb, bic, NBIC);
    // ---- u_local = normalize(Hu * bic)
    gather_norm<<<cdiv(NUSERS, RPB), BLK, 0, stream>>>(start + HU_BASE, cnt + HU_BASE, edges,
                                                       bic, ulocal, NUSERS);
    // ---- layer 3 + epilogue -> out
    gather_final<<<cdiv(NTOT, RPB), BLK, 0, stream>>>(start, cnt, edges,
                                                      T0, T1, user_emb, item_emb,
                                                      ulocal, (float*)d_out);
}